// Round 8
// baseline (208.897 us; speedup 1.0000x reference)
//
#include <hip/hip_runtime.h>

typedef float2 cplx;

constexpr float TWO_PI = 6.28318530717958647692f;

__device__ inline void cmac(float& ax, float& ay, cplx a, cplx b) {
    ax += a.x * b.x - a.y * b.y;
    ay += a.x * b.y + a.y * b.x;
}

// ---- K_pre: A, Bq, Cq, e1, e2, h (+ per-wave mean/var partials of h) --------
__global__ __launch_bounds__(256) void k_pre(
    const float* __restrict__ x, const float* __restrict__ fc0_w,
    const float* __restrict__ fc0_b,
    const float* __restrict__ p1r, const float* __restrict__ p1i,
    const float* __restrict__ p2r, const float* __restrict__ p2i,
    const float* __restrict__ resr, const float* __restrict__ resi,
    const float* __restrict__ t_grid, const float* __restrict__ x_grid,
    cplx* __restrict__ A, cplx* __restrict__ Bq, cplx* __restrict__ Cq,
    cplx* __restrict__ e1, cplx* __restrict__ e2,
    float* __restrict__ h, float* __restrict__ accH2)
{
    int idx = blockIdx.x * 256 + threadIdx.x;
    float dty = x_grid[1] - x_grid[0];
    float dtx = t_grid[1] - t_grid[0];
    const int NA = 65536, NBQ = 81920, NCQ = 81920, NE1 = 65536, NE2 = 81920;
    if (idx < NA) {
        int p = idx & 3, k = (idx >> 2) & 15, i = (idx >> 6) & 15, o = idx >> 10;
        int kf = (o < 32) ? o : o - 64;
        float om = TWO_PI * (float)kf / (64.f * dty);
        float dr = -p1r[(i * 16 + k) * 4 + p], di = om - p1i[(i * 16 + k) * 4 + p];
        float inv = 1.f / (dr * dr + di * di);
        A[idx] = make_float2(dr * inv, -di * inv);
        return;
    }
    idx -= NA;
    if (idx < NBQ) {
        int q = idx % 5, k = (idx / 5) & 15, i = (idx / 80) & 15, xx = idx / 1280;
        int kf = (xx < 32) ? xx : xx - 64;
        float om = TWO_PI * (float)kf / (64.f * dtx);
        float dr = -p2r[(i * 16 + k) * 5 + q], di = om - p2i[(i * 16 + k) * 5 + q];
        float inv = 1.f / (dr * dr + di * di);
        Bq[idx] = make_float2(dr * inv, -di * inv);
        return;
    }
    idx -= NBQ;
    if (idx < NCQ) {
        int q = idx % 5, k = (idx / 5) & 15, i = (idx / 80) & 15, o = idx / 1280;
        int kf = (o < 32) ? o : o - 64;
        float om = TWO_PI * (float)kf / (64.f * dty);
        float cx = 0.f, cy = 0.f;
        for (int p = 0; p < 4; ++p) {
            float dr = -p1r[(i * 16 + k) * 4 + p], di = om - p1i[(i * 16 + k) * 4 + p];
            float inv = 1.f / (dr * dr + di * di);
            float axr = dr * inv, axi = -di * inv;
            float rr = resr[((i * 16 + k) * 4 + p) * 5 + q];
            float ri = resi[((i * 16 + k) * 4 + p) * 5 + q];
            cx += rr * axr - ri * axi;
            cy += rr * axi + ri * axr;
        }
        Cq[idx] = make_float2(cx, cy);
        return;
    }
    idx -= NCQ;
    if (idx < NE1) {
        int z = idx & 63, w = idx >> 6;
        float t = x_grid[z];
        float m = expf(p1r[w] * t);
        float sn, cs; sincosf(p1i[w] * t, &sn, &cs);
        e1[idx] = make_float2(m * cs, m * sn);
        return;
    }
    idx -= NE1;
    if (idx < NE2) {
        int xx = idx & 63, w = idx >> 6;
        float t = t_grid[xx];
        float m = expf(p2r[w] * t);
        float sn, cs; sincosf(p2i[w] * t, &sn, &cs);
        e2[idx] = make_float2(m * cs, m * sn);
        return;
    }
    idx -= NE2;
    {   // h = fc0(x,gx,gy) + per-wave mean/var partials (NO atomics)
        int bc = idx >> 12, pix = idx & 4095;
        int b = bc >> 4, c = bc & 15;
        int z = pix >> 6, xx = pix & 63;
        const float inv63 = 1.f / 63.f;
        float v = fc0_w[c * 3] * x[b * 4096 + pix]
                + fc0_w[c * 3 + 1] * (z * inv63)
                + fc0_w[c * 3 + 2] * (xx * inv63) + fc0_b[c];
        h[idx] = v;
        float s = v, s2 = v * v;
        for (int m = 32; m; m >>= 1) {
            s  += __shfl_xor(s,  m, 64);
            s2 += __shfl_xor(s2, m, 64);
        }
        if ((threadIdx.x & 63) == 0) {
            int widx = pix >> 6;              // 0..63, wave-unique per bc
            accH2[bc * 128 + widx * 2]     = s;
            accH2[bc * 128 + widx * 2 + 1] = s2;
        }
    }
}

// ---- kFFT: fused fftA+fftB per (bc, 8 p-rows). T1 in LDS only. --------------
// alpha[p][q] = sum_j [ rstd*(sum_i h[i][j]W^(pi) - 64 mean d_p0) ] W^(qj)
__global__ __launch_bounds__(256) void kFFT(
    const float* __restrict__ h, const float* __restrict__ accH2,
    cplx* __restrict__ alpha, cplx* __restrict__ alphaT)
{
    __shared__ float hs[4096];       // 16 KB
    __shared__ cplx  T1s[512];       // 8 rows x 64
    __shared__ cplx  Ws[64];
    __shared__ float mv[2];
    int bc = blockIdx.x >> 3, pg = blockIdx.x & 7;
    int tid = threadIdx.x;
    if (tid < 64) { float sn, cs; sincosf(-TWO_PI * tid / 64.f, &sn, &cs); Ws[tid] = make_float2(cs, sn); }
    else if (tid < 128) {
        int l = tid - 64;
        float s  = accH2[bc * 128 + l * 2];
        float s2 = accH2[bc * 128 + l * 2 + 1];
        for (int m = 32; m; m >>= 1) { s += __shfl_xor(s, m, 64); s2 += __shfl_xor(s2, m, 64); }
        if (l == 0) {
            float mean = s * (1.f / 4096.f);
            float var  = s2 * (1.f / 4096.f) - mean * mean;
            mv[0] = mean; mv[1] = rsqrtf(var + 1e-5f);
        }
    }
    for (int t = 0; t < 16; ++t) hs[t * 256 + tid] = h[bc * 4096 + t * 256 + tid];
    __syncthreads();
    float mean = mv[0], rstd = mv[1];
    // phase A: T1 rows (2 per thread), dual accumulators
    for (int t = 0; t < 2; ++t) {
        int idx = t * 256 + tid;
        int pl = idx >> 6, j = idx & 63;
        int p = pg * 8 + pl;
        float ax0 = 0.f, ay0 = 0.f, ax1 = 0.f, ay1 = 0.f;
        #pragma unroll
        for (int i = 0; i < 64; i += 2) {
            float v0 = hs[i * 64 + j];       cplx w0 = Ws[(p * i) & 63];
            ax0 += v0 * w0.x; ay0 += v0 * w0.y;
            float v1 = hs[(i + 1) * 64 + j]; cplx w1 = Ws[(p * (i + 1)) & 63];
            ax1 += v1 * w1.x; ay1 += v1 * w1.y;
        }
        float ax = ax0 + ax1, ay = ay0 + ay1;
        if (p == 0) ax -= 64.f * mean;
        T1s[pl * 64 + j] = make_float2(ax * rstd, ay * rstd);
    }
    __syncthreads();
    // phase B: alpha rows (2 per thread), dual accumulators
    for (int t = 0; t < 2; ++t) {
        int idx = t * 256 + tid;
        int pl = idx >> 6, q = idx & 63;
        int p = pg * 8 + pl;
        float ax0 = 0.f, ay0 = 0.f, ax1 = 0.f, ay1 = 0.f;
        const cplx* trow = &T1s[pl * 64];
        #pragma unroll
        for (int j = 0; j < 64; j += 2) {
            cmac(ax0, ay0, trow[j],     Ws[(q * j) & 63]);
            cmac(ax1, ay1, trow[j + 1], Ws[(q * (j + 1)) & 63]);
        }
        cplx v = make_float2(ax0 + ax1, ay0 + ay1);
        alpha [bc * 4096 + p * 64 + q] = v;
        alphaT[(p * 64 + q) * 64 + bc] = v;
    }
}

// ---- K3: fused G+r1 per (o,x): G[i][k]=sum_q Cq*Bq; r1[b,k]=sum_i a[b,i]*G --
__global__ __launch_bounds__(64) void k3_r1(
    const cplx* __restrict__ alphaT, const cplx* __restrict__ Cq,
    const cplx* __restrict__ Bq, cplx* __restrict__ r1)
{
    __shared__ cplx Cqs[1280], Bqs[1280], Gs[256], as[64];
    int ox = blockIdx.x; int o = ox >> 6, xx = ox & 63;
    int t = threadIdx.x;
    for (int m = 0; m < 20; ++m) {
        Cqs[m * 64 + t] = Cq[o * 1280 + m * 64 + t];
        Bqs[m * 64 + t] = Bq[xx * 1280 + m * 64 + t];
    }
    as[t] = alphaT[ox * 64 + t];
    __syncthreads();
    for (int m = 0; m < 4; ++m) {
        int e = m * 64 + t; int i = e >> 4, k = e & 15;
        float gx = 0.f, gy = 0.f;
        for (int q = 0; q < 5; ++q) cmac(gx, gy, Cqs[i * 80 + k * 5 + q], Bqs[i * 80 + k * 5 + q]);
        Gs[e] = make_float2(gx, gy);
    }
    __syncthreads();
    int b = t >> 4, k = t & 15;
    float ax0 = 0.f, ay0 = 0.f, ax1 = 0.f, ay1 = 0.f;
    #pragma unroll
    for (int i = 0; i < 16; i += 2) {
        cmac(ax0, ay0, as[b * 16 + i],     Gs[i * 16 + k]);
        cmac(ax1, ay1, as[b * 16 + i + 1], Gs[(i + 1) * 16 + k]);
    }
    r1[t * 4096 + ox] = make_float2(ax0 + ax1, ay0 + ay1);
}

// ---- k45_r2: fused inner1+r2 per (b,k); 1024 thr = (i 0..15, o 0..63) -------
__global__ __launch_bounds__(1024) void k45_r2(
    const cplx* __restrict__ alpha, const cplx* __restrict__ Bq,
    const cplx* __restrict__ A,
    const float* __restrict__ resr, const float* __restrict__ resi,
    cplx* __restrict__ r2)
{
    __shared__ cplx red[16][20];
    int bk = blockIdx.x; int b = bk >> 4, k = bk & 15;
    int o = threadIdx.x & 63, i = threadIdx.x >> 6;
    // inner[q] = sum_x alpha[(b*16+i)][o][x] * Bq[x][i][k][q]
    float inx[5] = {}, iny[5] = {};
    const cplx* arow = alpha + (b * 16 + i) * 4096 + o * 64;
    const cplx* bq   = Bq + i * 80 + k * 5;
    #pragma unroll 4
    for (int xx = 0; xx < 64; ++xx) {
        cplx av = arow[xx];
        const cplx* bv = bq + xx * 1280;     // wave-uniform -> broadcast
        for (int q = 0; q < 5; ++q) {
            inx[q] += av.x * bv[q].x - av.y * bv[q].y;
            iny[q] += av.x * bv[q].y + av.y * bv[q].x;
        }
    }
    float accx[4][5], accy[4][5];
    int rb = (i * 16 + k) * 20;
    for (int p = 0; p < 4; ++p) {
        cplx a = A[((o * 16 + i) * 16 + k) * 4 + p];
        for (int q = 0; q < 5; ++q) {
            float tx = a.x * inx[q] - a.y * iny[q];
            float ty = a.x * iny[q] + a.y * inx[q];
            float rr = resr[rb + p * 5 + q], ri = resi[rb + p * 5 + q];
            accx[p][q] = rr * tx - ri * ty;
            accy[p][q] = rr * ty + ri * tx;
        }
    }
    for (int m = 32; m; m >>= 1)
        for (int p = 0; p < 4; ++p)
            for (int q = 0; q < 5; ++q) {
                accx[p][q] += __shfl_xor(accx[p][q], m, 64);
                accy[p][q] += __shfl_xor(accy[p][q], m, 64);
            }
    if (o == 0)
        for (int p = 0; p < 4; ++p)
            for (int q = 0; q < 5; ++q)
                red[i][p * 5 + q] = make_float2(accx[p][q], accy[p][q]);
    __syncthreads();
    if (threadIdx.x < 20) {
        float sx = 0.f, sy = 0.f;
        for (int g = 0; g < 16; ++g) { sx += red[g][threadIdx.x].x; sy += red[g][threadIdx.x].y; }
        r2[bk * 20 + threadIdx.x] = make_float2(sx, sy);
    }
}

// ---- k78_sp: fused ifftA+ifftB+V per (bc, 8 z-rows); T2 in LDS only ---------
__global__ __launch_bounds__(256) void k78_sp(
    const cplx* __restrict__ r1, const cplx* __restrict__ r2,
    const cplx* __restrict__ e1, const cplx* __restrict__ e2,
    float* __restrict__ sp, float* __restrict__ accS2)
{
    __shared__ cplx rs[4096];        // 32 KB: r1[bc] tile
    __shared__ cplx T2s[512];        // 8 z-rows x 64
    __shared__ cplx Vs[640];         // [bq 0..79][zl 0..7]
    __shared__ cplx Ws[64];
    int bc = blockIdx.x >> 3, zg = blockIdx.x & 7;
    int b = bc >> 4, ch = bc & 15;
    int tid = threadIdx.x;
    if (tid < 64) { float sn, cs; sincosf(TWO_PI * tid / 64.f, &sn, &cs); Ws[tid] = make_float2(cs, sn); }
    for (int t = 0; t < 16; ++t) rs[t * 256 + tid] = r1[bc * 4096 + t * 256 + tid];
    // V slice: Vs[bq*8+zl] = sum_p r2[(b*16+bb)*20+p*5+q] * e1[((bb*16+ch)*4+p)*64+z]
    for (int e = tid; e < 640; e += 256) {
        int zl = e & 7, bq = e >> 3;
        int bb = bq / 5, q = bq - bb * 5;
        int z = zg * 8 + zl;
        float vx = 0.f, vy = 0.f;
        for (int p = 0; p < 4; ++p)
            cmac(vx, vy, r2[(b * 16 + bb) * 20 + p * 5 + q],
                         e1[((bb * 16 + ch) * 4 + p) * 64 + z]);
        Vs[bq * 8 + zl] = make_float2(vx, vy);
    }
    __syncthreads();
    // T2 rows: T2s[zl][j] = sum_o rs[o][j] * W^(z*o)
    for (int t = 0; t < 2; ++t) {
        int idx = t * 256 + tid;
        int zl = idx >> 6, j = idx & 63;
        int z = zg * 8 + zl;
        float ax0 = 0.f, ay0 = 0.f, ax1 = 0.f, ay1 = 0.f;
        #pragma unroll
        for (int o = 0; o < 64; o += 2) {
            cmac(ax0, ay0, rs[o * 64 + j],       Ws[(z * o) & 63]);
            cmac(ax1, ay1, rs[(o + 1) * 64 + j], Ws[(z * (o + 1)) & 63]);
        }
        T2s[zl * 64 + j] = make_float2(ax0 + ax1, ay0 + ay1);
    }
    __syncthreads();
    // pixels: 2 per thread; ifftB + V*e2; per-wave stat partials
    float s = 0.f, s2 = 0.f;
    for (int t = 0; t < 2; ++t) {
        int lp = t * 256 + tid;
        int zl = lp >> 6, xx = lp & 63;       // zl wave-uniform
        float ax0 = 0.f, ax1 = 0.f;
        const cplx* trow = &T2s[zl * 64];
        #pragma unroll
        for (int j = 0; j < 64; j += 2) {
            cplx v0 = trow[j];     cplx w0 = Ws[(xx * j) & 63];
            ax0 += v0.x * w0.x - v0.y * w0.y;
            cplx v1 = trow[j + 1]; cplx w1 = Ws[(xx * (j + 1)) & 63];
            ax1 += v1.x * w1.x - v1.y * w1.y;
        }
        float acc = ax0 + ax1;
        const cplx* eb = e2 + ch * 320 + xx;
        #pragma unroll 4
        for (int bb = 0; bb < 16; ++bb)
            for (int q = 0; q < 5; ++q) {
                cplx vv = Vs[(bb * 5 + q) * 8 + zl];   // broadcast
                cplx ee = eb[bb * 5120 + q * 64];      // coalesced L2
                acc += vv.x * ee.x - vv.y * ee.y;
            }
        float val = acc * (1.f / 4096.f);
        sp[bc * 4096 + zg * 512 + lp] = val;
        s += val; s2 += val * val;
    }
    for (int m = 32; m; m >>= 1) {
        s  += __shfl_xor(s,  m, 64);
        s2 += __shfl_xor(s2, m, 64);
    }
    if ((tid & 63) == 0) {
        int widx = zg * 4 + (tid >> 6);       // 0..31, wave-unique per bc
        accS2[bc * 64 + widx * 2]     = s;
        accS2[bc * 64 + widx * 2 + 1] = s2;
    }
}

// ---- K9: out = fc2( sin( fc1( inorm(sp) + w0*h + w0_b ) ) ) -----------------
__global__ __launch_bounds__(256) void k9_final(
    const float* __restrict__ sp, const float* __restrict__ accS2,
    const float* __restrict__ h,
    const float* __restrict__ w0_w, const float* __restrict__ w0_b,
    const float* __restrict__ fc1_w, const float* __restrict__ fc1_b,
    const float* __restrict__ fc2_w, const float* __restrict__ fc2_b,
    float* __restrict__ out)
{
    __shared__ float w1s[128 * 16], b1s[128], w2s[128], w0s[256], w0bs[16];
    __shared__ float mvm[16], mvr[16];
    int tid = threadIdx.x;
    int b = blockIdx.x >> 4;            // 16 blocks per batch
    for (int t = 0; t < 8; ++t) w1s[t * 256 + tid] = fc1_w[t * 256 + tid];
    if (tid < 128) { b1s[tid] = fc1_b[tid]; w2s[tid] = fc2_w[tid]; }
    w0s[tid] = w0_w[tid & 255];
    if (tid < 16) w0bs[tid] = w0_b[tid];
    // stats: 4 waves x 4 channels, reduce 32 partials per channel
    {
        int wv = tid >> 6, ln = tid & 63;
        for (int cc = 0; cc < 4; ++cc) {
            int c = wv * 4 + cc;
            float s = 0.f, s2 = 0.f;
            if (ln < 32) {
                s  = accS2[(b * 16 + c) * 64 + ln * 2];
                s2 = accS2[(b * 16 + c) * 64 + ln * 2 + 1];
            }
            for (int m = 16; m; m >>= 1) { s += __shfl_xor(s, m, 64); s2 += __shfl_xor(s2, m, 64); }
            if (ln == 0) {
                float mean = s * (1.f / 4096.f);
                float var  = s2 * (1.f / 4096.f) - mean * mean;
                mvm[c] = mean; mvr[c] = rsqrtf(var + 1e-5f);
            }
        }
    }
    float b2 = fc2_b[0];
    __syncthreads();
    int pix = blockIdx.x * 256 + tid;    // 0..16383
    int rem = pix & 4095;
    float hv[16], tv[16];
    for (int c = 0; c < 16; ++c) {
        hv[c] = h[(b * 16 + c) * 4096 + rem];
        tv[c] = (sp[(b * 16 + c) * 4096 + rem] - mvm[c]) * mvr[c];
    }
    for (int k = 0; k < 16; ++k) {
        float a = w0bs[k];
        for (int c = 0; c < 16; ++c) a += w0s[k * 16 + c] * hv[c];
        tv[k] += a;
    }
    float acc = b2;
    for (int n = 0; n < 128; ++n) {
        float s1 = b1s[n];
        for (int k2 = 0; k2 < 16; ++k2) s1 += w1s[n * 16 + k2] * tv[k2];
        acc += w2s[n] * sinf(s1);
    }
    out[pix] = acc;
}

extern "C" void kernel_launch(void* const* d_in, const int* in_sizes, int n_in,
                              void* d_out, int out_size, void* d_ws, size_t ws_size,
                              hipStream_t stream)
{
    const float* x     = (const float*)d_in[0];
    const float* fc0_w = (const float*)d_in[1];
    const float* fc0_b = (const float*)d_in[2];
    const float* p1r   = (const float*)d_in[3];
    const float* p1i   = (const float*)d_in[4];
    const float* p2r   = (const float*)d_in[5];
    const float* p2i   = (const float*)d_in[6];
    const float* resr  = (const float*)d_in[7];
    const float* resi  = (const float*)d_in[8];
    const float* w0_w  = (const float*)d_in[9];
    const float* w0_b  = (const float*)d_in[10];
    const float* fc1_w = (const float*)d_in[11];
    const float* fc1_b = (const float*)d_in[12];
    const float* fc2_w = (const float*)d_in[13];
    const float* fc2_b = (const float*)d_in[14];
    const float* t_grid= (const float*)d_in[15];
    const float* x_grid= (const float*)d_in[16];
    float* out = (float*)d_out;

    float* ws = (float*)d_ws;
    size_t off = 0;
    float* h      = ws + off; off += 262144;            // (64,4096)
    cplx*  alpha  = (cplx*)(ws + off); off += 524288;   // [bi][o][x] c
    cplx*  alphaT = (cplx*)(ws + off); off += 524288;   // [ox][bi] c
    cplx*  A      = (cplx*)(ws + off); off += 131072;   // (64,16,16,4) c
    cplx*  Bq     = (cplx*)(ws + off); off += 163840;   // (64,16,16,5) c
    cplx*  Cq     = (cplx*)(ws + off); off += 163840;   // (64,16,16,5) c
    cplx*  e1     = (cplx*)(ws + off); off += 131072;   // (16,16,4,64) c
    cplx*  e2     = (cplx*)(ws + off); off += 163840;   // (16,16,5,64) c
    cplx*  r1     = (cplx*)(ws + off); off += 524288;   // [bk][o][x] c
    cplx*  r2     = (cplx*)(ws + off); off += 2560;     // (4,16,4,5) c
    float* sp     = ws + off; off += 262144;
    float* accH2  = ws + off; off += 8192;              // [bc][64 waves][2]
    float* accS2  = ws + off; off += 4096;              // [bc][32 waves][2]
    (void)ws_size; (void)n_in; (void)in_sizes; (void)out_size;

    k_pre<<<2496, 256, 0, stream>>>(x, fc0_w, fc0_b, p1r, p1i, p2r, p2i, resr, resi,
                                    t_grid, x_grid, A, Bq, Cq, e1, e2, h, accH2);
    kFFT<<<512, 256, 0, stream>>>(h, accH2, alpha, alphaT);
    k3_r1<<<4096, 64, 0, stream>>>(alphaT, Cq, Bq, r1);
    k45_r2<<<64, 1024, 0, stream>>>(alpha, Bq, A, resr, resi, r2);
    k78_sp<<<512, 256, 0, stream>>>(r1, r2, e1, e2, sp, accS2);
    k9_final<<<64, 256, 0, stream>>>(sp, accS2, h, w0_w, w0_b, fc1_w, fc1_b, fc2_w, fc2_b, out);
}